// Round 10
// baseline (521.130 us; speedup 1.0000x reference)
//
#include <hip/hip_runtime.h>
#include <hip/hip_bf16.h>
#include <math.h>

// Problem constants (LightGFormer): B=16, N=512, D=256, L=4, H=8, dk=32, Dff=1024
#define BDIM 16
#define NSEQ 512
#define DMODEL 256
#define NLAYER 4
#define NHEAD 8
#define DK 32
#define DFF 1024
#define BN (BDIM * NSEQ)          // 8192 tokens
#define ND (NSEQ * DMODEL)        // 131072

typedef __bf16 bf16x8 __attribute__((ext_vector_type(8)));
typedef float floatx4 __attribute__((ext_vector_type(4)));

// RNE float->bf16 bits
static __device__ __forceinline__ unsigned short f2bf(float f) {
    unsigned u = __float_as_uint(f);
    unsigned r = (u + 0x7FFFu + ((u >> 16) & 1u)) >> 16;
    return (unsigned short)r;
}

// async 16-byte global->LDS copy (wave-uniform LDS base + lane*16 required)
static __device__ __forceinline__ void async_ld16(const unsigned short* g,
                                                  unsigned short* l) {
    __builtin_amdgcn_global_load_lds(
        (const __attribute__((address_space(1))) unsigned int*)g,
        (__attribute__((address_space(3))) unsigned int*)l, 16, 0, 0);
}

// sigmoid-form tanh-approx GELU, |err| < 1e-3 vs exact
static __device__ __forceinline__ float gelu_f(float c) {
    float u = 0.7978845608028654f * (c + 0.044715f * c * c * c);
    return c * (1.f / (1.f + __expf(-2.f * u)));
}

// ---------------------------------------------------------------------------
// All four 256x256 weight families in one launch (Wq,Wk,Wv,Wo): [L,K,N]->[L,N,K]
// ---------------------------------------------------------------------------
__global__ void conv_qkvo_kernel(const float* __restrict__ s0, const float* __restrict__ s1,
                                 const float* __restrict__ s2, const float* __restrict__ s3,
                                 unsigned short* __restrict__ d0, unsigned short* __restrict__ d1,
                                 unsigned short* __restrict__ d2, unsigned short* __restrict__ d3) {
    int i = blockIdx.x * 256 + threadIdx.x;       // 0 .. 4*262144-1
    int sel = i >> 18;
    int j = i & 262143;
    int l = j >> 16;
    int rem = j & 65535;
    int k = rem >> 8, n = rem & 255;
    const float* src = sel == 0 ? s0 : sel == 1 ? s1 : sel == 2 ? s2 : s3;
    unsigned short* dst = sel == 0 ? d0 : sel == 1 ? d1 : sel == 2 ? d2 : d3;
    dst[(size_t)l * 65536 + n * 256 + k] = f2bf(src[j]);
}

// W1 [4,256,1024] and W2 [4,512,128] transposed-bf16 in one launch
__global__ void conv_w12_kernel(const float* __restrict__ W1, const float* __restrict__ W2,
                                unsigned short* __restrict__ w1T, unsigned short* __restrict__ w2T) {
    int i = blockIdx.x * 256 + threadIdx.x;
    if (i < 4 * 262144) {
        int l = i >> 18, rem = i & 262143, k = rem >> 10, n = rem & 1023;
        w1T[(size_t)l * 262144 + (size_t)n * 256 + k] = f2bf(W1[i]);
    } else {
        int j = i - 4 * 262144;
        if (j < 4 * 65536) {
            int l = j >> 16, rem = j & 65535, k = rem >> 7, n = rem & 127;
            w2T[(size_t)l * 65536 + (size_t)n * 512 + k] = f2bf(W2[j]);
        }
    }
}

// mask (int 512x512) -> bitmask (512 x 16 uint32); bit=1 -> -inf
__global__ void conv_mask_kernel(const int* __restrict__ mask,
                                 unsigned* __restrict__ bits) {
    int w = blockIdx.x * blockDim.x + threadIdx.x; // 0..8191
    int r = w >> 4, wi = w & 15;
    const int* src = mask + r * NSEQ + wi * 32;
    unsigned acc = 0;
#pragma unroll
    for (int j = 0; j < 32; j++) acc |= (src[j] != 0 ? 1u : 0u) << j;
    bits[w] = acc;
}

// ---------------------------------------------------------------------------
// x = input + pos (fp32 + bf16) ; xv = input_v + pos (bf16 only)
// ---------------------------------------------------------------------------
__global__ void add_pos_kernel(const float* __restrict__ in,
                               const float* __restrict__ inv,
                               const float* __restrict__ pos,
                               float* __restrict__ x,
                               unsigned short* __restrict__ xb,
                               unsigned short* __restrict__ xvb,
                               int total) {
    int i = blockIdx.x * blockDim.x + threadIdx.x;
    if (i < total) {
        float pe = pos[i % ND];
        float a = in[i] + pe;
        float b = inv[i] + pe;
        x[i] = a;
        xb[i] = f2bf(a);
        xvb[i] = f2bf(b);
    }
}

// ---------------------------------------------------------------------------
// Fused QKV GEMM: grid (6, 64). blockIdx.x: 0,1->Q  2,3->K  4,5->V.
// Output bf16 head-blocked: [(row/512)*8 + col/32][row%512][col%32]
// ---------------------------------------------------------------------------
__global__ __launch_bounds__(256) void qkv_mfma_kernel(
        const unsigned short* __restrict__ xb,
        const unsigned short* __restrict__ xvb,
        const unsigned short* __restrict__ WqT, const unsigned short* __restrict__ WkT,
        const unsigned short* __restrict__ WvT,
        const float* __restrict__ bq, const float* __restrict__ bk,
        const float* __restrict__ bv,
        unsigned short* __restrict__ qo, unsigned short* __restrict__ ko,
        unsigned short* __restrict__ vo) {
    int proj = blockIdx.x >> 1;
    const unsigned short* A  = (proj == 2) ? xvb : xb;
    const unsigned short* Bt = (proj == 0) ? WqT : (proj == 1) ? WkT : WvT;
    const float* bias        = (proj == 0) ? bq  : (proj == 1) ? bk  : bv;
    unsigned short* Cb       = (proj == 0) ? qo  : (proj == 1) ? ko  : vo;

    __shared__ unsigned short As[128 * 32];
    __shared__ unsigned short Bs[128 * 32];
    int tid = threadIdx.x;
    int wave = tid >> 6, lane = tid & 63;
    int rowBase = blockIdx.y * 128, colBase = (blockIdx.x & 1) * 128;
    int m0w = (wave & 1) * 64, n0w = (wave >> 1) * 64;
    int lr = lane & 15, quad = lane >> 4;

    floatx4 acc[4][4];
#pragma unroll
    for (int mi = 0; mi < 4; mi++)
#pragma unroll
        for (int nj = 0; nj < 4; nj++) acc[mi][nj] = (floatx4)0.0f;

    for (int kt = 0; kt < DMODEL; kt += 32) {
#pragma unroll
        for (int t = 0; t < 2; t++) {
            int idx = t * 256 + tid;
            int row = idx >> 2, kv8 = (idx & 3) * 8;
            async_ld16(A + (size_t)(rowBase + row) * DMODEL + kt + kv8, &As[idx * 8]);
            async_ld16(Bt + (size_t)(colBase + row) * DMODEL + kt + kv8, &Bs[idx * 8]);
        }
        __syncthreads();
        bf16x8 af[4], bfr[4];
#pragma unroll
        for (int mi = 0; mi < 4; mi++)
            af[mi] = *(const bf16x8*)&As[(m0w + mi * 16 + lr) * 32 + quad * 8];
#pragma unroll
        for (int nj = 0; nj < 4; nj++)
            bfr[nj] = *(const bf16x8*)&Bs[(n0w + nj * 16 + lr) * 32 + quad * 8];
#pragma unroll
        for (int mi = 0; mi < 4; mi++)
#pragma unroll
            for (int nj = 0; nj < 4; nj++)
                acc[mi][nj] = __builtin_amdgcn_mfma_f32_16x16x32_bf16(
                    af[mi], bfr[nj], acc[mi][nj], 0, 0, 0);
        __syncthreads();
    }

#pragma unroll
    for (int mi = 0; mi < 4; mi++) {
#pragma unroll
        for (int r = 0; r < 4; r++) {
            int grow = rowBase + m0w + mi * 16 + quad * 4 + r;
#pragma unroll
            for (int nj = 0; nj < 4; nj++) {
                int gcol = colBase + n0w + nj * 16 + lr;
                float c = acc[mi][nj][r] + bias[gcol];
                size_t off = ((size_t)((grow >> 9) * 8 + (gcol >> 5)) << 14)
                           + (size_t)(grow & 511) * 32 + (gcol & 31);
                Cb[off] = f2bf(c);
            }
        }
    }
}

// ---------------------------------------------------------------------------
// Generic MFMA GEMM (FFN1): C = A @ Bt^T + bias, optional GELU, bf16 out.
// ---------------------------------------------------------------------------
__global__ __launch_bounds__(256) void gemm_mfma_kernel(
        const unsigned short* __restrict__ A,
        const unsigned short* __restrict__ Bt,
        const float* __restrict__ bias,
        unsigned short* __restrict__ Cb,
        int M, int K, int N, int act) {
    __shared__ unsigned short As[128 * 32];
    __shared__ unsigned short Bs[128 * 32];
    int tid = threadIdx.x;
    int wave = tid >> 6, lane = tid & 63;
    int rowBase = blockIdx.y * 128, colBase = blockIdx.x * 128;
    int m0w = (wave & 1) * 64, n0w = (wave >> 1) * 64;
    int lr = lane & 15, quad = lane >> 4;

    floatx4 acc[4][4];
#pragma unroll
    for (int mi = 0; mi < 4; mi++)
#pragma unroll
        for (int nj = 0; nj < 4; nj++) acc[mi][nj] = (floatx4)0.0f;

    for (int kt = 0; kt < K; kt += 32) {
#pragma unroll
        for (int t = 0; t < 2; t++) {
            int idx = t * 256 + tid;
            int row = idx >> 2, kv8 = (idx & 3) * 8;
            async_ld16(A + (size_t)(rowBase + row) * K + kt + kv8, &As[idx * 8]);
            async_ld16(Bt + (size_t)(colBase + row) * K + kt + kv8, &Bs[idx * 8]);
        }
        __syncthreads();
        bf16x8 af[4], bfr[4];
#pragma unroll
        for (int mi = 0; mi < 4; mi++)
            af[mi] = *(const bf16x8*)&As[(m0w + mi * 16 + lr) * 32 + quad * 8];
#pragma unroll
        for (int nj = 0; nj < 4; nj++)
            bfr[nj] = *(const bf16x8*)&Bs[(n0w + nj * 16 + lr) * 32 + quad * 8];
#pragma unroll
        for (int mi = 0; mi < 4; mi++)
#pragma unroll
            for (int nj = 0; nj < 4; nj++)
                acc[mi][nj] = __builtin_amdgcn_mfma_f32_16x16x32_bf16(
                    af[mi], bfr[nj], acc[mi][nj], 0, 0, 0);
        __syncthreads();
    }

#pragma unroll
    for (int mi = 0; mi < 4; mi++) {
#pragma unroll
        for (int r = 0; r < 4; r++) {
            int grow = rowBase + m0w + mi * 16 + quad * 4 + r;
#pragma unroll
            for (int nj = 0; nj < 4; nj++) {
                int gcol = colBase + n0w + nj * 16 + lr;
                float c = acc[mi][nj][r] + bias[gcol];
                if (act) c = gelu_f(c);
                Cb[(size_t)grow * N + gcol] = f2bf(c);
            }
        }
    }
}

// ---------------------------------------------------------------------------
// Fused Wo-GEMM + bias + residual + LayerNorm. 32 rows x 256 cols, 256 thr,
// 4 waves split column-wise (64 cols each); LN reduce via LDS across waves.
// ---------------------------------------------------------------------------
__global__ __launch_bounds__(256) void wo_ln_kernel(
        const unsigned short* __restrict__ A,     // ab_b [8192][256]
        const unsigned short* __restrict__ Bt,    // woT [256][256]
        const float* __restrict__ bias,
        const float* __restrict__ g, const float* __restrict__ be,
        float* __restrict__ xf, unsigned short* __restrict__ xb) {
    __shared__ unsigned short As[32 * 32];
    __shared__ unsigned short Bs[256 * 32];
    __shared__ float redS[32][4], redQ[32][4];
    int tid = threadIdx.x;
    int wave = tid >> 6, lane = tid & 63, l16 = lane & 15, quad = lane >> 4;
    int rowBase = blockIdx.x * 32;
    int cw = wave * 64;

    floatx4 acc[2][4];
#pragma unroll
    for (int mg = 0; mg < 2; mg++)
#pragma unroll
        for (int t = 0; t < 4; t++) acc[mg][t] = (floatx4)0.0f;

    for (int kt = 0; kt < 256; kt += 32) {
        if (tid < 128) {  // waves 0,1 stage As (wave-uniform branch): 128*8 = 32x32
            int row = tid >> 2, kv8 = (tid & 3) * 8;
            async_ld16(A + (size_t)(rowBase + row) * 256 + kt + kv8, &As[tid * 8]);
        }
#pragma unroll
        for (int t = 0; t < 4; t++) {   // 4*256*8 = 256x32  (R9 bug: was t<2)
            int idx = t * 256 + tid;
            int row = idx >> 2, kv8 = (idx & 3) * 8;
            async_ld16(Bt + (size_t)row * 256 + kt + kv8, &Bs[idx * 8]);
        }
        __syncthreads();
        bf16x8 af[2], bfr[4];
#pragma unroll
        for (int mg = 0; mg < 2; mg++)
            af[mg] = *(const bf16x8*)&As[(mg * 16 + l16) * 32 + quad * 8];
#pragma unroll
        for (int t = 0; t < 4; t++)
            bfr[t] = *(const bf16x8*)&Bs[(cw + t * 16 + l16) * 32 + quad * 8];
#pragma unroll
        for (int mg = 0; mg < 2; mg++)
#pragma unroll
            for (int t = 0; t < 4; t++)
                acc[mg][t] = __builtin_amdgcn_mfma_f32_16x16x32_bf16(
                    af[mg], bfr[t], acc[mg][t], 0, 0, 0);
        __syncthreads();
    }

    float bcol[4], gc[4], bec[4];
#pragma unroll
    for (int t = 0; t < 4; t++) {
        int c = cw + t * 16 + l16;
        bcol[t] = bias[c]; gc[t] = g[c]; bec[t] = be[c];
    }
#pragma unroll
    for (int mg = 0; mg < 2; mg++) {
#pragma unroll
        for (int r = 0; r < 4; r++) {
            int row = mg * 16 + quad * 4 + r;
            int grow = rowBase + row;
            float s = 0.f, s2 = 0.f;
#pragma unroll
            for (int t = 0; t < 4; t++) {
                float val = acc[mg][t][r] + bcol[t]
                          + xf[(size_t)grow * 256 + cw + t * 16 + l16];
                acc[mg][t][r] = val;
                s += val; s2 += val * val;
            }
#pragma unroll
            for (int off = 1; off <= 8; off <<= 1) {
                s += __shfl_xor(s, off);
                s2 += __shfl_xor(s2, off);
            }
            if (l16 == 0) { redS[row][wave] = s; redQ[row][wave] = s2; }
        }
    }
    __syncthreads();

#pragma unroll
    for (int mg = 0; mg < 2; mg++) {
#pragma unroll
        for (int r = 0; r < 4; r++) {
            int row = mg * 16 + quad * 4 + r;
            int grow = rowBase + row;
            float ts = redS[row][0] + redS[row][1] + redS[row][2] + redS[row][3];
            float tq = redQ[row][0] + redQ[row][1] + redQ[row][2] + redQ[row][3];
            float mean = ts * (1.f / 256.f);
            float var = tq * (1.f / 256.f) - mean * mean;
            float rstd = rsqrtf(var + 1e-5f);
#pragma unroll
            for (int t = 0; t < 4; t++) {
                int c = cw + t * 16 + l16;
                float o = (acc[mg][t][r] - mean) * rstd * gc[t] + bec[t];
                xf[(size_t)grow * 256 + c] = o;
                xb[(size_t)grow * 256 + c] = f2bf(o);
            }
        }
    }
}

// ---------------------------------------------------------------------------
// Fused FFN2(grouped) + bias + residual + LayerNorm. 64 rows x 128 cols,
// 256 thr, 4 waves split column-wise (32 cols each).
// ---------------------------------------------------------------------------
__global__ __launch_bounds__(256) void ffn2_ln_kernel(
        const unsigned short* __restrict__ A,     // h_b [16384][512]
        const unsigned short* __restrict__ Bt,    // w2T [128][512]
        const float* __restrict__ bias,           // [128]
        const float* __restrict__ g, const float* __restrict__ be,
        float* __restrict__ xf, unsigned short* __restrict__ xb) {
    __shared__ unsigned short As[64 * 32];
    __shared__ unsigned short Bs[128 * 32];
    __shared__ float redS[64][4], redQ[64][4];
    int tid = threadIdx.x;
    int wave = tid >> 6, lane = tid & 63, l16 = lane & 15, quad = lane >> 4;
    int rowBase = blockIdx.x * 64;
    int cw = wave * 32;

    floatx4 acc[4][2];
#pragma unroll
    for (int mg = 0; mg < 4; mg++)
#pragma unroll
        for (int t = 0; t < 2; t++) acc[mg][t] = (floatx4)0.0f;

    for (int kt = 0; kt < 512; kt += 32) {
        {
            int row = tid >> 2, kv8 = (tid & 3) * 8;   // 256*8 = 64x32
            async_ld16(A + (size_t)(rowBase + row) * 512 + kt + kv8, &As[tid * 8]);
        }
#pragma unroll
        for (int t = 0; t < 2; t++) {                  // 2*256*8 = 128x32
            int idx = t * 256 + tid;
            int row = idx >> 2, kv8 = (idx & 3) * 8;
            async_ld16(Bt + (size_t)row * 512 + kt + kv8, &Bs[idx * 8]);
        }
        __syncthreads();
        bf16x8 af[4], bfr[2];
#pragma unroll
        for (int mg = 0; mg < 4; mg++)
            af[mg] = *(const bf16x8*)&As[(mg * 16 + l16) * 32 + quad * 8];
#pragma unroll
        for (int t = 0; t < 2; t++)
            bfr[t] = *(const bf16x8*)&Bs[(cw + t * 16 + l16) * 32 + quad * 8];
#pragma unroll
        for (int mg = 0; mg < 4; mg++)
#pragma unroll
            for (int t = 0; t < 2; t++)
                acc[mg][t] = __builtin_amdgcn_mfma_f32_16x16x32_bf16(
                    af[mg], bfr[t], acc[mg][t], 0, 0, 0);
        __syncthreads();
    }

    float bcol[2];
#pragma unroll
    for (int t = 0; t < 2; t++) bcol[t] = bias[cw + t * 16 + l16];

#pragma unroll
    for (int mg = 0; mg < 4; mg++) {
#pragma unroll
        for (int r = 0; r < 4; r++) {
            int row = mg * 16 + quad * 4 + r;
            int grow = rowBase + row;
            int token = grow >> 1, dbase = (grow & 1) * 128;
            float s = 0.f, s2 = 0.f;
#pragma unroll
            for (int t = 0; t < 2; t++) {
                int c = cw + t * 16 + l16;
                float val = acc[mg][t][r] + bcol[t]
                          + xf[(size_t)token * 256 + dbase + c];
                acc[mg][t][r] = val;
                s += val; s2 += val * val;
            }
#pragma unroll
            for (int off = 1; off <= 8; off <<= 1) {
                s += __shfl_xor(s, off);
                s2 += __shfl_xor(s2, off);
            }
            if (l16 == 0) { redS[row][wave] = s; redQ[row][wave] = s2; }
        }
    }
    __syncthreads();

#pragma unroll
    for (int mg = 0; mg < 4; mg++) {
#pragma unroll
        for (int r = 0; r < 4; r++) {
            int row = mg * 16 + quad * 4 + r;
            int grow = rowBase + row;
            int token = grow >> 1, dbase = (grow & 1) * 128;
            float ts = 0.f, tq = 0.f;
#pragma unroll
            for (int w = 0; w < 4; w++) {
                ts += redS[row][w] + redS[row ^ 1][w];
                tq += redQ[row][w] + redQ[row ^ 1][w];
            }
            float mean = ts * (1.f / 256.f);
            float var = tq * (1.f / 256.f) - mean * mean;
            float rstd = rsqrtf(var + 1e-5f);
#pragma unroll
            for (int t = 0; t < 2; t++) {
                int d = dbase + cw + t * 16 + l16;
                float o = (acc[mg][t][r] - mean) * rstd * g[d] + be[d];
                xf[(size_t)token * 256 + d] = o;
                xb[(size_t)token * 256 + d] = f2bf(o);
            }
        }
    }
}

// ---------------------------------------------------------------------------
// MFMA attention v2. Grid = B*H*2 (query halves of 256); 256 thr = 4 waves,
// each wave owns 64 queries as 4 groups of 16. K/V^T fragments are
// query-independent: loaded once per 32-key chunk, reused by all 4 groups.
// ---------------------------------------------------------------------------
#define VTS 520
__global__ __launch_bounds__(256) void attn_mfma_kernel(
        const unsigned short* __restrict__ q, const unsigned short* __restrict__ k,
        const unsigned short* __restrict__ v, unsigned short* __restrict__ o,
        const unsigned* __restrict__ mbits_g, int use_mask) {
    int bid = blockIdx.x;
    int half = bid & 1, h = (bid >> 1) & 7, b = bid >> 4;
    int tid = threadIdx.x;

    __shared__ unsigned short Ks[NSEQ * DK];   // 32 KB
    __shared__ unsigned short Vt[DK * VTS];    // 32.5 KB

    const unsigned short* kbase = k + (size_t)(b * 8 + h) * (NSEQ * DK);
    const unsigned short* vbase = v + (size_t)(b * 8 + h) * (NSEQ * DK);

#pragma unroll
    for (int t = 0; t < 8; t++) {
        int idx = t * 256 + tid;
        async_ld16(kbase + (size_t)idx * 8, &Ks[idx * 8]);
    }
#pragma unroll
    for (int r = 0; r < 2; r++) {
        int kk = tid + r * 256;
        unsigned short tmp[32];
        *(uint4*)&tmp[0]  = *(const uint4*)(vbase + (size_t)kk * 32);
        *(uint4*)&tmp[8]  = *(const uint4*)(vbase + (size_t)kk * 32 + 8);
        *(uint4*)&tmp[16] = *(const uint4*)(vbase + (size_t)kk * 32 + 16);
        *(uint4*)&tmp[24] = *(const uint4*)(vbase + (size_t)kk * 32 + 24);
#pragma unroll
        for (int d = 0; d < 32; d++) Vt[d * VTS + kk] = tmp[d];
    }

    int wave = tid >> 6, lane = tid & 63, l16 = lane & 15, quad = lane >> 4;
    int qb0 = half * 256 + wave * 64;

    bf16x8 qf[4];
#pragma unroll
    for (int gq = 0; gq < 4; gq++)
        qf[gq] = *(const bf16x8*)(q + ((size_t)(b * 8 + h) * NSEQ + qb0 + gq * 16 + l16) * 32 + quad * 8);
    __syncthreads();

    floatx4 oT[4][2];
    float m_run[4], l_part[4];
#pragma unroll
    for (int gq = 0; gq < 4; gq++) {
        oT[gq][0] = (floatx4)0.f; oT[gq][1] = (floatx4)0.f;
        m_run[gq] = -INFINITY; l_part[gq] = 0.f;
    }
    const float scale = 0.17677669529663687f;

    for (int c = 0; c < 16; c++) {
        int kkb = c * 32;
        bf16x8 k0 = *(const bf16x8*)&Ks[(kkb + l16) * 32 + quad * 8];
        bf16x8 k1 = *(const bf16x8*)&Ks[(kkb + 16 + l16) * 32 + quad * 8];
        bf16x8 av0, av1;
        ((uint2*)&av0)[0] = *(const uint2*)&Vt[l16 * VTS + kkb + quad * 4];
        ((uint2*)&av0)[1] = *(const uint2*)&Vt[l16 * VTS + kkb + 16 + quad * 4];
        ((uint2*)&av1)[0] = *(const uint2*)&Vt[(16 + l16) * VTS + kkb + quad * 4];
        ((uint2*)&av1)[1] = *(const uint2*)&Vt[(16 + l16) * VTS + kkb + 16 + quad * 4];

#pragma unroll
        for (int gq = 0; gq < 4; gq++) {
            floatx4 s0 = __builtin_amdgcn_mfma_f32_16x16x32_bf16(k0, qf[gq], (floatx4)0.f, 0, 0, 0);
            floatx4 s1 = __builtin_amdgcn_mfma_f32_16x16x32_bf16(k1, qf[gq], (floatx4)0.f, 0, 0, 0);

            float sv[8];
#pragma unroll
            for (int r = 0; r < 4; r++) { sv[r] = s0[r] * scale; sv[4 + r] = s1[r] * scale; }
            if (use_mask) {
                unsigned wb = mbits_g[(size_t)(qb0 + gq * 16 + l16) * 16 + c];
#pragma unroll
                for (int r = 0; r < 4; r++) {
                    if ((wb >> (quad * 4 + r)) & 1) sv[r] = -INFINITY;
                    if ((wb >> (16 + quad * 4 + r)) & 1) sv[4 + r] = -INFINITY;
                }
            }
            float mx = sv[0];
#pragma unroll
            for (int j = 1; j < 8; j++) mx = fmaxf(mx, sv[j]);
            mx = fmaxf(mx, __shfl_xor(mx, 16));
            mx = fmaxf(mx, __shfl_xor(mx, 32));
            float mnew = fmaxf(m_run[gq], mx);
            float corr = (m_run[gq] == mnew) ? 1.f : __expf(m_run[gq] - mnew);
            l_part[gq] *= corr;
            oT[gq][0] *= corr; oT[gq][1] *= corr;
            float p[8];
#pragma unroll
            for (int j = 0; j < 8; j++) {
                float e = __expf(sv[j] - mnew);
                p[j] = (sv[j] > -INFINITY) ? e : 0.f;
                l_part[gq] += p[j];
            }
            union { bf16x8 v; unsigned short u[8]; } pf;
#pragma unroll
            for (int j = 0; j < 8; j++) pf.u[j] = f2bf(p[j]);

            oT[gq][0] = __builtin_amdgcn_mfma_f32_16x16x32_bf16(av0, pf.v, oT[gq][0], 0, 0, 0);
            oT[gq][1] = __builtin_amdgcn_mfma_f32_16x16x32_bf16(av1, pf.v, oT[gq][1], 0, 0, 0);
            m_run[gq] = mnew;
        }
    }

#pragma unroll
    for (int gq = 0; gq < 4; gq++) {
        float l = l_part[gq];
        l += __shfl_xor(l, 16);
        l += __shfl_xor(l, 32);
        float invl = (l > 0.f) ? 1.f / l : 0.f;
        unsigned short* orow = o + ((size_t)(b * NSEQ + qb0 + gq * 16 + l16)) * DMODEL + h * DK;
#pragma unroll
        for (int r = 0; r < 4; r++) {
            orow[quad * 4 + r]      = f2bf(oT[gq][0][r] * invl);
            orow[16 + quad * 4 + r] = f2bf(oT[gq][1][r] * invl);
        }
    }
}

// Final LN: out = LayerNorm(x) * gf + bf (fp32)
__global__ __launch_bounds__(256) void final_ln_kernel(
        const float* __restrict__ a,
        const float* __restrict__ g, const float* __restrict__ be,
        float* __restrict__ out) {
    int t = blockIdx.x;
    int d = threadIdx.x;
    size_t idx = (size_t)t * DMODEL + d;
    float v = a[idx];
    float s = v, s2 = v * v;
#pragma unroll
    for (int off = 32; off; off >>= 1) {
        s  += __shfl_xor(s, off);
        s2 += __shfl_xor(s2, off);
    }
    __shared__ float ws1[4], ws2[4];
    int wid = d >> 6;
    if ((d & 63) == 0) { ws1[wid] = s; ws2[wid] = s2; }
    __syncthreads();
    s  = ws1[0] + ws1[1] + ws1[2] + ws1[3];
    s2 = ws2[0] + ws2[1] + ws2[2] + ws2[3];
    float mean = s * (1.f / DMODEL);
    float var = s2 * (1.f / DMODEL) - mean * mean;
    float rstd = rsqrtf(var + 1e-5f);
    out[idx] = (v - mean) * rstd * g[d] + be[d];
}

// ---------------------------------------------------------------------------
extern "C" void kernel_launch(void* const* d_in, const int* in_sizes, int n_in,
                              void* d_out, int out_size, void* d_ws, size_t ws_size,
                              hipStream_t stream) {
    const float* input  = (const float*)d_in[0];
    const float* inputv = (const float*)d_in[1];
    const float* pos    = (const float*)d_in[2];
    const float* Wq = (const float*)d_in[3];
    const float* bq = (const float*)d_in[4];
    const float* Wk = (const float*)d_in[5];
    const float* bk = (const float*)d_in[6];
    const float* Wv = (const float*)d_in[7];
    const float* bv = (const float*)d_in[8];
    const float* Wo = (const float*)d_in[9];
    const float* bo = (const float*)d_in[10];
    const float* W1 = (const float*)d_in[11];
    const float* b1 = (const float*)d_in[12];
    const float* W2 = (const float*)d_in[13];
    const float* b2 = (const float*)d_in[14];
    const float* g1 = (const float*)d_in[15];
    const float* be1 = (const float*)d_in[16];
    const float* g2 = (const float*)d_in[17];
    const float* be2 = (const float*)d_in[18];
    const float* gf = (const float*)d_in[19];
    const float* bff = (const float*)d_in[20];
    const int* mask = (const int*)d_in[21];

    float* out = (float*)d_out;

    // Workspace layout (bytes), ~37 MB
    char* wsb = (char*)d_ws;
    float* x_f  = (float*)(wsb + ((size_t)0 << 20));                    // 8 MB
    unsigned short* x_b  = (unsigned short*)(wsb + ((size_t)8 << 20));  // 4 MB
    unsigned short* xv_b = (unsigned short*)(wsb + ((size_t)12 << 20)); // 4 MB
    unsigned short* qb_b = (unsigned short*)(wsb + ((size_t)16 << 20)); // 4 MB
    unsigned short* kb_b = (unsigned short*)(wsb + ((size_t)20 << 20)); // 4 MB
    unsigned short* vb_b = (unsigned short*)(wsb + ((size_t)24 << 20)); // 4 MB
    unsigned short* ab_b = (unsigned short*)(wsb + ((size_t)28 << 20)); // 4 MB
    unsigned short* h_b  = qb_b;  // 16 MB alias over qb..ab (dead during FFN)
    unsigned short* wqT = (unsigned short*)(wsb + ((size_t)32 << 20));
    unsigned short* wkT = wqT + (size_t)4 * 65536;
    unsigned short* wvT = wkT + (size_t)4 * 65536;
    unsigned short* woT = wvT + (size_t)4 * 65536;
    unsigned short* w1T = woT + (size_t)4 * 65536;   // 4 x 262144
    unsigned short* w2T = w1T + (size_t)4 * 262144;  // 4 x 65536
    unsigned* mbits = (unsigned*)(wsb + ((size_t)37 << 20));            // 32 KB

    const size_t TOK = (size_t)BN * DMODEL;

    // --- preconversions (4 dispatches) ---
    conv_qkvo_kernel<<<4096, 256, 0, stream>>>(Wq, Wk, Wv, Wo, wqT, wkT, wvT, woT);
    conv_w12_kernel<<<(4 * 262144 + 4 * 65536) / 256, 256, 0, stream>>>(W1, W2, w1T, w2T);
    conv_mask_kernel<<<8192 / 256, 256, 0, stream>>>(mask, mbits);
    add_pos_kernel<<<(int)((TOK + 255) / 256), 256, 0, stream>>>(
        input, inputv, pos, x_f, x_b, xv_b, (int)TOK);

    for (int i = 0; i < NLAYER; i++) {
        const unsigned short* WqT_i = wqT + (size_t)i * 65536;
        const unsigned short* WkT_i = wkT + (size_t)i * 65536;
        const unsigned short* WvT_i = wvT + (size_t)i * 65536;
        const unsigned short* WoT_i = woT + (size_t)i * 65536;
        const unsigned short* W1T_i = w1T + (size_t)i * 262144;
        const unsigned short* W2T_i = w2T + (size_t)i * 65536;

        qkv_mfma_kernel<<<dim3(6, 64), 256, 0, stream>>>(
            x_b, xv_b, WqT_i, WkT_i, WvT_i,
            bq + i * DMODEL, bk + i * DMODEL, bv + i * DMODEL,
            qb_b, kb_b, vb_b);

        attn_mfma_kernel<<<BDIM * NHEAD * 2, 256, 0, stream>>>(
            qb_b, kb_b, vb_b, ab_b, mbits, (i & 1));

        wo_ln_kernel<<<BN / 32, 256, 0, stream>>>(
            ab_b, WoT_i, bo + i * DMODEL,
            g1 + i * DMODEL, be1 + i * DMODEL, x_f, x_b);

        gemm_mfma_kernel<<<dim3(8, 64), 256, 0, stream>>>(
            x_b, W1T_i, b1 + i * DFF, h_b, BN, DMODEL, DFF, 1);

        ffn2_ln_kernel<<<(2 * BN) / 64, 256, 0, stream>>>(
            h_b, W2T_i, b2 + i * (DMODEL / 2),
            g2 + i * DMODEL, be2 + i * DMODEL, x_f, x_b);
    }

    final_ln_kernel<<<BN, DMODEL, 0, stream>>>(x_f, gf, bff, out);
}

// Round 12
// 512.164 us; speedup vs baseline: 1.0175x; 1.0175x over previous
//
#include <hip/hip_runtime.h>
#include <hip/hip_bf16.h>
#include <math.h>

// Problem constants (LightGFormer): B=16, N=512, D=256, L=4, H=8, dk=32, Dff=1024
#define BDIM 16
#define NSEQ 512
#define DMODEL 256
#define NLAYER 4
#define NHEAD 8
#define DK 32
#define DFF 1024
#define BN (BDIM * NSEQ)          // 8192 tokens
#define ND (NSEQ * DMODEL)        // 131072

typedef __bf16 bf16x8 __attribute__((ext_vector_type(8)));
typedef float floatx4 __attribute__((ext_vector_type(4)));

// RNE float->bf16 bits
static __device__ __forceinline__ unsigned short f2bf(float f) {
    unsigned u = __float_as_uint(f);
    unsigned r = (u + 0x7FFFu + ((u >> 16) & 1u)) >> 16;
    return (unsigned short)r;
}

// async 16-byte global->LDS copy (wave-uniform LDS base + lane*16 required)
static __device__ __forceinline__ void async_ld16(const unsigned short* g,
                                                  unsigned short* l) {
    __builtin_amdgcn_global_load_lds(
        (const __attribute__((address_space(1))) unsigned int*)g,
        (__attribute__((address_space(3))) unsigned int*)l, 16, 0, 0);
}

// sigmoid-form tanh-approx GELU, |err| < 1e-3 vs exact
static __device__ __forceinline__ float gelu_f(float c) {
    float u = 0.7978845608028654f * (c + 0.044715f * c * c * c);
    return c * (1.f / (1.f + __expf(-2.f * u)));
}

// ---------------------------------------------------------------------------
// All four 256x256 weight families in one launch (Wq,Wk,Wv,Wo): [L,K,N]->[L,N,K]
// ---------------------------------------------------------------------------
__global__ void conv_qkvo_kernel(const float* __restrict__ s0, const float* __restrict__ s1,
                                 const float* __restrict__ s2, const float* __restrict__ s3,
                                 unsigned short* __restrict__ d0, unsigned short* __restrict__ d1,
                                 unsigned short* __restrict__ d2, unsigned short* __restrict__ d3) {
    int i = blockIdx.x * 256 + threadIdx.x;       // 0 .. 4*262144-1
    int sel = i >> 18;
    int j = i & 262143;
    int l = j >> 16;
    int rem = j & 65535;
    int k = rem >> 8, n = rem & 255;
    const float* src = sel == 0 ? s0 : sel == 1 ? s1 : sel == 2 ? s2 : s3;
    unsigned short* dst = sel == 0 ? d0 : sel == 1 ? d1 : sel == 2 ? d2 : d3;
    dst[(size_t)l * 65536 + n * 256 + k] = f2bf(src[j]);
}

// W1 [4,256,1024] and W2 [4,512,128] transposed-bf16 in one launch
__global__ void conv_w12_kernel(const float* __restrict__ W1, const float* __restrict__ W2,
                                unsigned short* __restrict__ w1T, unsigned short* __restrict__ w2T) {
    int i = blockIdx.x * 256 + threadIdx.x;
    if (i < 4 * 262144) {
        int l = i >> 18, rem = i & 262143, k = rem >> 10, n = rem & 1023;
        w1T[(size_t)l * 262144 + (size_t)n * 256 + k] = f2bf(W1[i]);
    } else {
        int j = i - 4 * 262144;
        if (j < 4 * 65536) {
            int l = j >> 16, rem = j & 65535, k = rem >> 7, n = rem & 127;
            w2T[(size_t)l * 65536 + (size_t)n * 512 + k] = f2bf(W2[j]);
        }
    }
}

// mask (int 512x512) -> bitmask (512 x 16 uint32); bit=1 -> -inf
__global__ void conv_mask_kernel(const int* __restrict__ mask,
                                 unsigned* __restrict__ bits) {
    int w = blockIdx.x * blockDim.x + threadIdx.x; // 0..8191
    int r = w >> 4, wi = w & 15;
    const int* src = mask + r * NSEQ + wi * 32;
    unsigned acc = 0;
#pragma unroll
    for (int j = 0; j < 32; j++) acc |= (src[j] != 0 ? 1u : 0u) << j;
    bits[w] = acc;
}

// ---------------------------------------------------------------------------
// x = input + pos (fp32 + bf16) ; xv = input_v + pos (bf16 only)
// ---------------------------------------------------------------------------
__global__ void add_pos_kernel(const float* __restrict__ in,
                               const float* __restrict__ inv,
                               const float* __restrict__ pos,
                               float* __restrict__ x,
                               unsigned short* __restrict__ xb,
                               unsigned short* __restrict__ xvb,
                               int total) {
    int i = blockIdx.x * blockDim.x + threadIdx.x;
    if (i < total) {
        float pe = pos[i % ND];
        float a = in[i] + pe;
        float b = inv[i] + pe;
        x[i] = a;
        xb[i] = f2bf(a);
        xvb[i] = f2bf(b);
    }
}

// ---------------------------------------------------------------------------
// Fused QKV GEMM: grid (6, 64). blockIdx.x: 0,1->Q  2,3->K  4,5->V.
// Output bf16 head-blocked: [(row/512)*8 + col/32][row%512][col%32]
// ---------------------------------------------------------------------------
__global__ __launch_bounds__(256) void qkv_mfma_kernel(
        const unsigned short* __restrict__ xb,
        const unsigned short* __restrict__ xvb,
        const unsigned short* __restrict__ WqT, const unsigned short* __restrict__ WkT,
        const unsigned short* __restrict__ WvT,
        const float* __restrict__ bq, const float* __restrict__ bk,
        const float* __restrict__ bv,
        unsigned short* __restrict__ qo, unsigned short* __restrict__ ko,
        unsigned short* __restrict__ vo) {
    int proj = blockIdx.x >> 1;
    const unsigned short* A  = (proj == 2) ? xvb : xb;
    const unsigned short* Bt = (proj == 0) ? WqT : (proj == 1) ? WkT : WvT;
    const float* bias        = (proj == 0) ? bq  : (proj == 1) ? bk  : bv;
    unsigned short* Cb       = (proj == 0) ? qo  : (proj == 1) ? ko  : vo;

    __shared__ unsigned short As[128 * 32];
    __shared__ unsigned short Bs[128 * 32];
    int tid = threadIdx.x;
    int wave = tid >> 6, lane = tid & 63;
    int rowBase = blockIdx.y * 128, colBase = (blockIdx.x & 1) * 128;
    int m0w = (wave & 1) * 64, n0w = (wave >> 1) * 64;
    int lr = lane & 15, quad = lane >> 4;

    floatx4 acc[4][4];
#pragma unroll
    for (int mi = 0; mi < 4; mi++)
#pragma unroll
        for (int nj = 0; nj < 4; nj++) acc[mi][nj] = (floatx4)0.0f;

    for (int kt = 0; kt < DMODEL; kt += 32) {
#pragma unroll
        for (int t = 0; t < 2; t++) {
            int idx = t * 256 + tid;
            int row = idx >> 2, kv8 = (idx & 3) * 8;
            async_ld16(A + (size_t)(rowBase + row) * DMODEL + kt + kv8, &As[idx * 8]);
            async_ld16(Bt + (size_t)(colBase + row) * DMODEL + kt + kv8, &Bs[idx * 8]);
        }
        __syncthreads();
        bf16x8 af[4], bfr[4];
#pragma unroll
        for (int mi = 0; mi < 4; mi++)
            af[mi] = *(const bf16x8*)&As[(m0w + mi * 16 + lr) * 32 + quad * 8];
#pragma unroll
        for (int nj = 0; nj < 4; nj++)
            bfr[nj] = *(const bf16x8*)&Bs[(n0w + nj * 16 + lr) * 32 + quad * 8];
#pragma unroll
        for (int mi = 0; mi < 4; mi++)
#pragma unroll
            for (int nj = 0; nj < 4; nj++)
                acc[mi][nj] = __builtin_amdgcn_mfma_f32_16x16x32_bf16(
                    af[mi], bfr[nj], acc[mi][nj], 0, 0, 0);
        __syncthreads();
    }

#pragma unroll
    for (int mi = 0; mi < 4; mi++) {
#pragma unroll
        for (int r = 0; r < 4; r++) {
            int grow = rowBase + m0w + mi * 16 + quad * 4 + r;
#pragma unroll
            for (int nj = 0; nj < 4; nj++) {
                int gcol = colBase + n0w + nj * 16 + lr;
                float c = acc[mi][nj][r] + bias[gcol];
                size_t off = ((size_t)((grow >> 9) * 8 + (gcol >> 5)) << 14)
                           + (size_t)(grow & 511) * 32 + (gcol & 31);
                Cb[off] = f2bf(c);
            }
        }
    }
}

// ---------------------------------------------------------------------------
// Generic MFMA GEMM (FFN1): C = A @ Bt^T + bias, optional GELU, bf16 out.
// ---------------------------------------------------------------------------
__global__ __launch_bounds__(256) void gemm_mfma_kernel(
        const unsigned short* __restrict__ A,
        const unsigned short* __restrict__ Bt,
        const float* __restrict__ bias,
        unsigned short* __restrict__ Cb,
        int M, int K, int N, int act) {
    __shared__ unsigned short As[128 * 32];
    __shared__ unsigned short Bs[128 * 32];
    int tid = threadIdx.x;
    int wave = tid >> 6, lane = tid & 63;
    int rowBase = blockIdx.y * 128, colBase = blockIdx.x * 128;
    int m0w = (wave & 1) * 64, n0w = (wave >> 1) * 64;
    int lr = lane & 15, quad = lane >> 4;

    floatx4 acc[4][4];
#pragma unroll
    for (int mi = 0; mi < 4; mi++)
#pragma unroll
        for (int nj = 0; nj < 4; nj++) acc[mi][nj] = (floatx4)0.0f;

    for (int kt = 0; kt < K; kt += 32) {
#pragma unroll
        for (int t = 0; t < 2; t++) {
            int idx = t * 256 + tid;
            int row = idx >> 2, kv8 = (idx & 3) * 8;
            async_ld16(A + (size_t)(rowBase + row) * K + kt + kv8, &As[idx * 8]);
            async_ld16(Bt + (size_t)(colBase + row) * K + kt + kv8, &Bs[idx * 8]);
        }
        __syncthreads();
        bf16x8 af[4], bfr[4];
#pragma unroll
        for (int mi = 0; mi < 4; mi++)
            af[mi] = *(const bf16x8*)&As[(m0w + mi * 16 + lr) * 32 + quad * 8];
#pragma unroll
        for (int nj = 0; nj < 4; nj++)
            bfr[nj] = *(const bf16x8*)&Bs[(n0w + nj * 16 + lr) * 32 + quad * 8];
#pragma unroll
        for (int mi = 0; mi < 4; mi++)
#pragma unroll
            for (int nj = 0; nj < 4; nj++)
                acc[mi][nj] = __builtin_amdgcn_mfma_f32_16x16x32_bf16(
                    af[mi], bfr[nj], acc[mi][nj], 0, 0, 0);
        __syncthreads();
    }

#pragma unroll
    for (int mi = 0; mi < 4; mi++) {
#pragma unroll
        for (int r = 0; r < 4; r++) {
            int grow = rowBase + m0w + mi * 16 + quad * 4 + r;
#pragma unroll
            for (int nj = 0; nj < 4; nj++) {
                int gcol = colBase + n0w + nj * 16 + lr;
                float c = acc[mi][nj][r] + bias[gcol];
                if (act) c = gelu_f(c);
                Cb[(size_t)grow * N + gcol] = f2bf(c);
            }
        }
    }
}

// ---------------------------------------------------------------------------
// Fused Wo-GEMM + bias + residual + LayerNorm. 32 rows x 256 cols, 512 thr
// (8 waves, 32 cols each); LN reduce via LDS across waves.
// ---------------------------------------------------------------------------
__global__ __launch_bounds__(512) void wo_ln_kernel(
        const unsigned short* __restrict__ A,     // ab_b [8192][256]
        const unsigned short* __restrict__ Bt,    // woT [256][256]
        const float* __restrict__ bias,
        const float* __restrict__ g, const float* __restrict__ be,
        float* __restrict__ xf, unsigned short* __restrict__ xb) {
    __shared__ unsigned short As[32 * 32];
    __shared__ unsigned short Bs[256 * 32];
    __shared__ float redS[32][8], redQ[32][8];
    int tid = threadIdx.x;
    int wave = tid >> 6, lane = tid & 63, l16 = lane & 15, quad = lane >> 4;
    int rowBase = blockIdx.x * 32;
    int cw = wave * 32;

    floatx4 acc[2][2];
#pragma unroll
    for (int mg = 0; mg < 2; mg++)
#pragma unroll
        for (int t = 0; t < 2; t++) acc[mg][t] = (floatx4)0.0f;

    for (int kt = 0; kt < 256; kt += 32) {
        if (tid < 128) {  // 128*8 = 32x32
            int row = tid >> 2, kv8 = (tid & 3) * 8;
            async_ld16(A + (size_t)(rowBase + row) * 256 + kt + kv8, &As[tid * 8]);
        }
#pragma unroll
        for (int t = 0; t < 2; t++) {   // 2*512*8 = 256x32
            int idx = t * 512 + tid;
            int row = idx >> 2, kv8 = (idx & 3) * 8;
            async_ld16(Bt + (size_t)row * 256 + kt + kv8, &Bs[idx * 8]);
        }
        __syncthreads();
        bf16x8 af[2], bfr[2];
#pragma unroll
        for (int mg = 0; mg < 2; mg++)
            af[mg] = *(const bf16x8*)&As[(mg * 16 + l16) * 32 + quad * 8];
#pragma unroll
        for (int t = 0; t < 2; t++)
            bfr[t] = *(const bf16x8*)&Bs[(cw + t * 16 + l16) * 32 + quad * 8];
#pragma unroll
        for (int mg = 0; mg < 2; mg++)
#pragma unroll
            for (int t = 0; t < 2; t++)
                acc[mg][t] = __builtin_amdgcn_mfma_f32_16x16x32_bf16(
                    af[mg], bfr[t], acc[mg][t], 0, 0, 0);
        __syncthreads();
    }

    float bcol[2], gc[2], bec[2];
#pragma unroll
    for (int t = 0; t < 2; t++) {
        int c = cw + t * 16 + l16;
        bcol[t] = bias[c]; gc[t] = g[c]; bec[t] = be[c];
    }
#pragma unroll
    for (int mg = 0; mg < 2; mg++) {
#pragma unroll
        for (int r = 0; r < 4; r++) {
            int row = mg * 16 + quad * 4 + r;
            int grow = rowBase + row;
            float s = 0.f, s2 = 0.f;
#pragma unroll
            for (int t = 0; t < 2; t++) {
                float val = acc[mg][t][r] + bcol[t]
                          + xf[(size_t)grow * 256 + cw + t * 16 + l16];
                acc[mg][t][r] = val;
                s += val; s2 += val * val;
            }
#pragma unroll
            for (int off = 1; off <= 8; off <<= 1) {
                s += __shfl_xor(s, off);
                s2 += __shfl_xor(s2, off);
            }
            if (l16 == 0) { redS[row][wave] = s; redQ[row][wave] = s2; }
        }
    }
    __syncthreads();

#pragma unroll
    for (int mg = 0; mg < 2; mg++) {
#pragma unroll
        for (int r = 0; r < 4; r++) {
            int row = mg * 16 + quad * 4 + r;
            int grow = rowBase + row;
            float ts = 0.f, tq = 0.f;
#pragma unroll
            for (int w = 0; w < 8; w++) { ts += redS[row][w]; tq += redQ[row][w]; }
            float mean = ts * (1.f / 256.f);
            float var = tq * (1.f / 256.f) - mean * mean;
            float rstd = rsqrtf(var + 1e-5f);
#pragma unroll
            for (int t = 0; t < 2; t++) {
                int c = cw + t * 16 + l16;
                float o = (acc[mg][t][r] - mean) * rstd * gc[t] + bec[t];
                xf[(size_t)grow * 256 + c] = o;
                xb[(size_t)grow * 256 + c] = f2bf(o);
            }
        }
    }
}

// ---------------------------------------------------------------------------
// Fused FFN2(grouped) + bias + residual + LayerNorm. 64 rows x 128 cols,
// 512 thr (8 waves, 16 cols each).
// ---------------------------------------------------------------------------
__global__ __launch_bounds__(512) void ffn2_ln_kernel(
        const unsigned short* __restrict__ A,     // h_b [16384][512]
        const unsigned short* __restrict__ Bt,    // w2T [128][512]
        const float* __restrict__ bias,           // [128]
        const float* __restrict__ g, const float* __restrict__ be,
        float* __restrict__ xf, unsigned short* __restrict__ xb) {
    __shared__ unsigned short As[64 * 32];
    __shared__ unsigned short Bs[128 * 32];
    __shared__ float redS[64][8], redQ[64][8];
    int tid = threadIdx.x;
    int wave = tid >> 6, lane = tid & 63, l16 = lane & 15, quad = lane >> 4;
    int rowBase = blockIdx.x * 64;
    int cw = wave * 16;

    floatx4 acc[4];
#pragma unroll
    for (int mg = 0; mg < 4; mg++) acc[mg] = (floatx4)0.0f;

    for (int kt = 0; kt < 512; kt += 32) {
        if (tid < 256) {                       // 256*8 = 64x32
            int row = tid >> 2, kv8 = (tid & 3) * 8;
            async_ld16(A + (size_t)(rowBase + row) * 512 + kt + kv8, &As[tid * 8]);
        }
        {                                      // 512*8 = 128x32
            int row = tid >> 2, kv8 = (tid & 3) * 8;
            async_ld16(Bt + (size_t)row * 512 + kt + kv8, &Bs[tid * 8]);
        }
        __syncthreads();
        bf16x8 af[4];
#pragma unroll
        for (int mg = 0; mg < 4; mg++)
            af[mg] = *(const bf16x8*)&As[(mg * 16 + l16) * 32 + quad * 8];
        bf16x8 bfr = *(const bf16x8*)&Bs[(cw + l16) * 32 + quad * 8];
#pragma unroll
        for (int mg = 0; mg < 4; mg++)
            acc[mg] = __builtin_amdgcn_mfma_f32_16x16x32_bf16(
                af[mg], bfr, acc[mg], 0, 0, 0);
        __syncthreads();
    }

    float bcol = bias[cw + l16];

#pragma unroll
    for (int mg = 0; mg < 4; mg++) {
#pragma unroll
        for (int r = 0; r < 4; r++) {
            int row = mg * 16 + quad * 4 + r;
            int grow = rowBase + row;
            int token = grow >> 1, dbase = (grow & 1) * 128;
            float val = acc[mg][r] + bcol + xf[(size_t)token * 256 + dbase + cw + l16];
            acc[mg][r] = val;
            float s = val, s2 = val * val;
#pragma unroll
            for (int off = 1; off <= 8; off <<= 1) {
                s += __shfl_xor(s, off);
                s2 += __shfl_xor(s2, off);
            }
            if (l16 == 0) { redS[row][wave] = s; redQ[row][wave] = s2; }
        }
    }
    __syncthreads();

#pragma unroll
    for (int mg = 0; mg < 4; mg++) {
#pragma unroll
        for (int r = 0; r < 4; r++) {
            int row = mg * 16 + quad * 4 + r;
            int grow = rowBase + row;
            int token = grow >> 1, dbase = (grow & 1) * 128;
            float ts = 0.f, tq = 0.f;
#pragma unroll
            for (int w = 0; w < 8; w++) {
                ts += redS[row][w] + redS[row ^ 1][w];
                tq += redQ[row][w] + redQ[row ^ 1][w];
            }
            float mean = ts * (1.f / 256.f);
            float var = tq * (1.f / 256.f) - mean * mean;
            float rstd = rsqrtf(var + 1e-5f);
            int d = dbase + cw + l16;
            float o = (acc[mg][r] - mean) * rstd * g[d] + be[d];
            xf[(size_t)token * 256 + d] = o;
            xb[(size_t)token * 256 + d] = f2bf(o);
        }
    }
}

// ---------------------------------------------------------------------------
// MFMA attention v3. Grid = B*H*4 (query quarters of 128); 256 thr = 4 waves,
// each wave owns 32 queries as 2 groups of 16. 2 blocks/CU co-resident at
// 65 KB LDS -> 2 waves/SIMD. exp2-domain softmax.
// ---------------------------------------------------------------------------
#define VTS 520
__global__ __launch_bounds__(256) void attn_mfma_kernel(
        const unsigned short* __restrict__ q, const unsigned short* __restrict__ k,
        const unsigned short* __restrict__ v, unsigned short* __restrict__ o,
        const unsigned* __restrict__ mbits_g, int use_mask) {
    int bid = blockIdx.x;
    int quarter = bid & 3, h = (bid >> 2) & 7, b = bid >> 5;
    int tid = threadIdx.x;

    __shared__ unsigned short Ks[NSEQ * DK];   // 32 KB
    __shared__ unsigned short Vt[DK * VTS];    // 32.5 KB

    const unsigned short* kbase = k + (size_t)(b * 8 + h) * (NSEQ * DK);
    const unsigned short* vbase = v + (size_t)(b * 8 + h) * (NSEQ * DK);

#pragma unroll
    for (int t = 0; t < 8; t++) {
        int idx = t * 256 + tid;
        async_ld16(kbase + (size_t)idx * 8, &Ks[idx * 8]);
    }
#pragma unroll
    for (int r = 0; r < 2; r++) {
        int kk = tid + r * 256;
        unsigned short tmp[32];
        *(uint4*)&tmp[0]  = *(const uint4*)(vbase + (size_t)kk * 32);
        *(uint4*)&tmp[8]  = *(const uint4*)(vbase + (size_t)kk * 32 + 8);
        *(uint4*)&tmp[16] = *(const uint4*)(vbase + (size_t)kk * 32 + 16);
        *(uint4*)&tmp[24] = *(const uint4*)(vbase + (size_t)kk * 32 + 24);
#pragma unroll
        for (int d = 0; d < 32; d++) Vt[d * VTS + kk] = tmp[d];
    }

    int wave = tid >> 6, lane = tid & 63, l16 = lane & 15, quad = lane >> 4;
    int qb0 = quarter * 128 + wave * 32;

    bf16x8 qf[2];
#pragma unroll
    for (int gq = 0; gq < 2; gq++)
        qf[gq] = *(const bf16x8*)(q + ((size_t)(b * 8 + h) * NSEQ + qb0 + gq * 16 + l16) * 32 + quad * 8);
    __syncthreads();

    floatx4 oT[2][2];
    float m_run[2], l_part[2];
#pragma unroll
    for (int gq = 0; gq < 2; gq++) {
        oT[gq][0] = (floatx4)0.f; oT[gq][1] = (floatx4)0.f;
        m_run[gq] = -INFINITY; l_part[gq] = 0.f;
    }
    // scale * log2(e): softmax computed in exp2 domain
    const float scale2 = 0.25503492f;

    for (int c = 0; c < 16; c++) {
        int kkb = c * 32;
        bf16x8 k0 = *(const bf16x8*)&Ks[(kkb + l16) * 32 + quad * 8];
        bf16x8 k1 = *(const bf16x8*)&Ks[(kkb + 16 + l16) * 32 + quad * 8];
        bf16x8 av0, av1;
        ((uint2*)&av0)[0] = *(const uint2*)&Vt[l16 * VTS + kkb + quad * 4];
        ((uint2*)&av0)[1] = *(const uint2*)&Vt[l16 * VTS + kkb + 16 + quad * 4];
        ((uint2*)&av1)[0] = *(const uint2*)&Vt[(16 + l16) * VTS + kkb + quad * 4];
        ((uint2*)&av1)[1] = *(const uint2*)&Vt[(16 + l16) * VTS + kkb + 16 + quad * 4];

#pragma unroll
        for (int gq = 0; gq < 2; gq++) {
            floatx4 s0 = __builtin_amdgcn_mfma_f32_16x16x32_bf16(k0, qf[gq], (floatx4)0.f, 0, 0, 0);
            floatx4 s1 = __builtin_amdgcn_mfma_f32_16x16x32_bf16(k1, qf[gq], (floatx4)0.f, 0, 0, 0);

            float sv[8];
#pragma unroll
            for (int r = 0; r < 4; r++) { sv[r] = s0[r] * scale2; sv[4 + r] = s1[r] * scale2; }
            if (use_mask) {
                unsigned wb = mbits_g[(size_t)(qb0 + gq * 16 + l16) * 16 + c];
#pragma unroll
                for (int r = 0; r < 4; r++) {
                    if ((wb >> (quad * 4 + r)) & 1) sv[r] = -INFINITY;
                    if ((wb >> (16 + quad * 4 + r)) & 1) sv[4 + r] = -INFINITY;
                }
            }
            float mx = sv[0];
#pragma unroll
            for (int j = 1; j < 8; j++) mx = fmaxf(mx, sv[j]);
            mx = fmaxf(mx, __shfl_xor(mx, 16));
            mx = fmaxf(mx, __shfl_xor(mx, 32));
            float mnew = fmaxf(m_run[gq], mx);
            float corr = (m_run[gq] == mnew) ? 1.f : exp2f(m_run[gq] - mnew);
            l_part[gq] *= corr;
            oT[gq][0] *= corr; oT[gq][1] *= corr;
            float p[8];
#pragma unroll
            for (int j = 0; j < 8; j++) {
                float e = exp2f(sv[j] - mnew);
                p[j] = (sv[j] > -INFINITY) ? e : 0.f;
                l_part[gq] += p[j];
            }
            union { bf16x8 v; unsigned short u[8]; } pf;
#pragma unroll
            for (int j = 0; j < 8; j++) pf.u[j] = f2bf(p[j]);

            oT[gq][0] = __builtin_amdgcn_mfma_f32_16x16x32_bf16(av0, pf.v, oT[gq][0], 0, 0, 0);
            oT[gq][1] = __builtin_amdgcn_mfma_f32_16x16x32_bf16(av1, pf.v, oT[gq][1], 0, 0, 0);
            m_run[gq] = mnew;
        }
    }

#pragma unroll
    for (int gq = 0; gq < 2; gq++) {
        float l = l_part[gq];
        l += __shfl_xor(l, 16);
        l += __shfl_xor(l, 32);
        float invl = (l > 0.f) ? 1.f / l : 0.f;
        unsigned short* orow = o + ((size_t)(b * NSEQ + qb0 + gq * 16 + l16)) * DMODEL + h * DK;
#pragma unroll
        for (int r = 0; r < 4; r++) {
            orow[quad * 4 + r]      = f2bf(oT[gq][0][r] * invl);
            orow[16 + quad * 4 + r] = f2bf(oT[gq][1][r] * invl);
        }
    }
}

// Final LN: out = LayerNorm(x) * gf + bf (fp32)
__global__ __launch_bounds__(256) void final_ln_kernel(
        const float* __restrict__ a,
        const float* __restrict__ g, const float* __restrict__ be,
        float* __restrict__ out) {
    int t = blockIdx.x;
    int d = threadIdx.x;
    size_t idx = (size_t)t * DMODEL + d;
    float v = a[idx];
    float s = v, s2 = v * v;
#pragma unroll
    for (int off = 32; off; off >>= 1) {
        s  += __shfl_xor(s, off);
        s2 += __shfl_xor(s2, off);
    }
    __shared__ float ws1[4], ws2[4];
    int wid = d >> 6;
    if ((d & 63) == 0) { ws1[wid] = s; ws2[wid] = s2; }
    __syncthreads();
    s  = ws1[0] + ws1[1] + ws1[2] + ws1[3];
    s2 = ws2[0] + ws2[1] + ws2[2] + ws2[3];
    float mean = s * (1.f / DMODEL);
    float var = s2 * (1.f / DMODEL) - mean * mean;
    float rstd = rsqrtf(var + 1e-5f);
    out[idx] = (v - mean) * rstd * g[d] + be[d];
}

// ---------------------------------------------------------------------------
extern "C" void kernel_launch(void* const* d_in, const int* in_sizes, int n_in,
                              void* d_out, int out_size, void* d_ws, size_t ws_size,
                              hipStream_t stream) {
    const float* input  = (const float*)d_in[0];
    const float* inputv = (const float*)d_in[1];
    const float* pos    = (const float*)d_in[2];
    const float* Wq = (const float*)d_in[3];
    const float* bq = (const float*)d_in[4];
    const float* Wk = (const float*)d_in[5];
    const float* bk = (const float*)d_in[6];
    const float* Wv = (const float*)d_in[7];
    const float* bv = (const float*)d_in[8];
    const float* Wo = (const float*)d_in[9];
    const float* bo = (const float*)d_in[10];
    const float* W1 = (const float*)d_in[11];
    const float* b1 = (const float*)d_in[12];
    const float* W2 = (const float*)d_in[13];
    const float* b2 = (const float*)d_in[14];
    const float* g1 = (const float*)d_in[15];
    const float* be1 = (const float*)d_in[16];
    const float* g2 = (const float*)d_in[17];
    const float* be2 = (const float*)d_in[18];
    const float* gf = (const float*)d_in[19];
    const float* bff = (const float*)d_in[20];
    const int* mask = (const int*)d_in[21];

    float* out = (float*)d_out;

    // Workspace layout (bytes), ~37 MB
    char* wsb = (char*)d_ws;
    float* x_f  = (float*)(wsb + ((size_t)0 << 20));                    // 8 MB
    unsigned short* x_b  = (unsigned short*)(wsb + ((size_t)8 << 20));  // 4 MB
    unsigned short* xv_b = (unsigned short*)(wsb + ((size_t)12 << 20)); // 4 MB
    unsigned short* qb_b = (unsigned short*)(wsb + ((size_t)16 << 20)); // 4 MB
    unsigned short* kb_b = (unsigned short*)(wsb + ((size_t)20 << 20)); // 4 MB
    unsigned short* vb_b = (unsigned short*)(wsb + ((size_t)24 << 20)); // 4 MB
    unsigned short* ab_b = (unsigned short*)(wsb + ((size_t)28 << 20)); // 4 MB
    unsigned short* h_b  = qb_b;  // 16 MB alias over qb..ab (dead during FFN)
    unsigned short* wqT = (unsigned short*)(wsb + ((size_t)32 << 20));
    unsigned short* wkT = wqT + (size_t)4 * 65536;
    unsigned short* wvT = wkT + (size_t)4 * 65536;
    unsigned short* woT = wvT + (size_t)4 * 65536;
    unsigned short* w1T = woT + (size_t)4 * 65536;   // 4 x 262144
    unsigned short* w2T = w1T + (size_t)4 * 262144;  // 4 x 65536
    unsigned* mbits = (unsigned*)(wsb + ((size_t)37 << 20));            // 32 KB

    const size_t TOK = (size_t)BN * DMODEL;

    // --- preconversions (4 dispatches) ---
    conv_qkvo_kernel<<<4096, 256, 0, stream>>>(Wq, Wk, Wv, Wo, wqT, wkT, wvT, woT);
    conv_w12_kernel<<<(4 * 262144 + 4 * 65536) / 256, 256, 0, stream>>>(W1, W2, w1T, w2T);
    conv_mask_kernel<<<8192 / 256, 256, 0, stream>>>(mask, mbits);
    add_pos_kernel<<<(int)((TOK + 255) / 256), 256, 0, stream>>>(
        input, inputv, pos, x_f, x_b, xv_b, (int)TOK);

    for (int i = 0; i < NLAYER; i++) {
        const unsigned short* WqT_i = wqT + (size_t)i * 65536;
        const unsigned short* WkT_i = wkT + (size_t)i * 65536;
        const unsigned short* WvT_i = wvT + (size_t)i * 65536;
        const unsigned short* WoT_i = woT + (size_t)i * 65536;
        const unsigned short* W1T_i = w1T + (size_t)i * 262144;
        const unsigned short* W2T_i = w2T + (size_t)i * 65536;

        qkv_mfma_kernel<<<dim3(6, 64), 256, 0, stream>>>(
            x_b, xv_b, WqT_i, WkT_i, WvT_i,
            bq + i * DMODEL, bk + i * DMODEL, bv + i * DMODEL,
            qb_b, kb_b, vb_b);

        attn_mfma_kernel<<<BDIM * NHEAD * 4, 256, 0, stream>>>(
            qb_b, kb_b, vb_b, ab_b, mbits, (i & 1));

        wo_ln_kernel<<<BN / 32, 512, 0, stream>>>(
            ab_b, WoT_i, bo + i * DMODEL,
            g1 + i * DMODEL, be1 + i * DMODEL, x_f, x_b);

        gemm_mfma_kernel<<<dim3(8, 64), 256, 0, stream>>>(
            x_b, W1T_i, b1 + i * DFF, h_b, BN, DMODEL, DFF, 1);

        ffn2_ln_kernel<<<(2 * BN) / 64, 512, 0, stream>>>(
            h_b, W2T_i, b2 + i * (DMODEL / 2),
            g2 + i * DMODEL, be2 + i * DMODEL, x_f, x_b);
    }

    final_ln_kernel<<<BN, DMODEL, 0, stream>>>(x_f, gf, bff, out);
}